// Round 14
// baseline (3770.878 us; speedup 1.0000x reference)
//
// R14 == R12 resubmission (container died before execution in R12/R13)
#include <hip/hip_runtime.h>
#include <hip/hip_bf16.h>
#include <cstdint>

#define BATCH 4096
#define DIM   512
#define HID   1024
#define TSTEPS 20
#define NBLK  128
#define NTHR  512

typedef unsigned short u16;
typedef short s16x8 __attribute__((ext_vector_type(8)));
typedef float f32x4 __attribute__((ext_vector_type(4)));

__device__ __forceinline__ u16 f2bf(float f) {
    unsigned int u = __float_as_uint(f);
    u = (u + 0x7FFFu + ((u >> 16) & 1u)) >> 16;   // RNE
    return (u16)u;
}

__device__ __forceinline__ float fast_tanh(float x) {
    float ax = __builtin_fabsf(x);
    float e  = __expf(2.0f * ax);                 // inf for large ax -> t = 1
    float t  = 1.0f - 2.0f * __builtin_amdgcn_rcpf(e + 1.0f);
    return __builtin_copysignf(t, x);
}

// out[0] = x0 ; ybf = bf16(x0)
__global__ void init_state(const float* __restrict__ x0, float* __restrict__ out0,
                           u16* __restrict__ ybf, int n) {
    int i = blockIdx.x * blockDim.x + threadIdx.x;
    if (i < n) { float v = x0[i]; out0[i] = v; ybf[i] = f2bf(v); }
}

// Pack W1 [512k][1024n] f32 -> W1P bf16 in MFMA B-frag order:
// u16 idx = (((w*16 + ks)*8 + cg)*64 + lane)*8 + e
__global__ void pack_w1(const float* __restrict__ W1, u16* __restrict__ W1P) {
    int pid = blockIdx.x * 256 + threadIdx.x;
    int e  = pid & 7;
    int l  = (pid >> 3) & 63;
    int cg = (pid >> 9) & 7;
    int ks = (pid >> 12) & 15;
    int w  = (pid >> 16) & 7;
    int n = w * 128 + cg * 16 + (l & 15);
    int k = ks * 32 + (l >> 4) * 8 + e;
    W1P[pid] = f2bf(W1[(size_t)k * HID + n]);
}

// Pack W2 [1024k][512n] f32 -> W2P bf16:
// u16 idx = (((w*32 + ks)*4 + cf)*64 + lane)*8 + e
__global__ void pack_w2(const float* __restrict__ W2, u16* __restrict__ W2P) {
    int pid = blockIdx.x * 256 + threadIdx.x;
    int e  = pid & 7;
    int l  = (pid >> 3) & 63;
    int cf = (pid >> 9) & 3;
    int ks = (pid >> 11) & 31;
    int w  = (pid >> 16) & 7;
    int n = w * 64 + cf * 16 + (l & 15);
    int k = ks * 32 + (l >> 4) * 8 + e;
    W2P[pid] = f2bf(W2[(size_t)k * DIM + n]);
}

// Fused RK4 stage: one launch computes k = f(y_arg) for all 4096 rows and
// applies the stage's epilogue. Block = 32-row strip, 512 threads.
// LDS frag-tile layout (16r x 32k tile contiguous 1KB; elem (r,k) at
// ((k>>3)&3)*128 + r*8 + (k&7)) -> all ds_read_b128 conflict-free.
__global__ __launch_bounds__(NTHR, 2) void ode_stage(
    const u16* __restrict__ ybf,          // y-arg bf16 [4096][512] (in-place updated)
    const float* __restrict__ b1, const float* __restrict__ b2,
    const u16* __restrict__ W1P, const u16* __restrict__ W2P,
    const float* __restrict__ ybase_g,    // trajectory slot s (f32)
    float* __restrict__ ynext_g,          // trajectory slot s+1 (f32)
    float* __restrict__ accum,            // f32 [4096][512] k-accumulator
    u16* __restrict__ ybf_next,           // == ybf (block-local in-place)
    const float* __restrict__ tgrid, int step, int st)
{
    __shared__ u16 hs[64 * 512];   // 64 KiB: h strip [32r][1024h], 64 frag-tiles
    __shared__ u16 ys[32 * 512];   // 32 KiB: y strip [32r][512k],  32 frag-tiles

    const int tid  = threadIdx.x;
    const int lane = tid & 63;
    const int w    = tid >> 6;            // wave 0..7
    const int row0 = blockIdx.x * 32;
    const int lr   = (lane >> 4) * 4;
    const int lc   = lane & 15;
    const int q    = lane >> 4;

    // ---- load y strip (bf16 global, coalesced) -> ys frag-tiles ----
#pragma unroll
    for (int t_ = 0; t_ < 4; ++t_) {
        int c  = tid + t_ * NTHR;             // 16B chunk id, 0..2047
        int r  = c >> 6;                      // 0..31
        int k0 = (c & 63) * 8;                // 0..504
        s16x8 v = *(const s16x8*)(ybf + (size_t)(row0 + r) * DIM + k0);
        int tile = (k0 >> 5) * 2 + (r >> 4);
        int off  = tile * 512 + ((k0 >> 3) & 3) * 128 + (r & 15) * 8;
        *(s16x8*)&ys[off] = v;
    }

    float bv1[8], bv2[4];
#pragma unroll
    for (int cg = 0; cg < 8; ++cg) bv1[cg] = b1[w * 128 + cg * 16 + lc];
#pragma unroll
    for (int cf = 0; cf < 4; ++cf) bv2[cf] = b2[w * 64 + cf * 16 + lc];

    const u16* p1 = W1P + ((size_t)w << 16) + lane * 8;   // + (ks*8+cg)*512
    const u16* p2 = W2P + ((size_t)w << 16) + lane * 8;   // + (ks*4+cf)*512

    __syncthreads();

    // ========== phase 1: h = tanh(y @ W1 + b1) -> hs  (wave: 32r x 128c, K=512) ==========
    {
        f32x4 acc1[2][8];
#pragma unroll
        for (int m = 0; m < 2; ++m)
#pragma unroll
            for (int cg = 0; cg < 8; ++cg)
                acc1[m][cg] = (f32x4){0.f, 0.f, 0.f, 0.f};

        s16x8 bA[8], bB[8];
#pragma unroll
        for (int cg = 0; cg < 8; ++cg)
            bA[cg] = *(const s16x8*)(p1 + cg * 512);

#pragma unroll
        for (int ks = 0; ks < 16; ++ks) {
            s16x8* bc = (ks & 1) ? bB : bA;
            s16x8* bn = (ks & 1) ? bA : bB;
            if (ks < 15) {
#pragma unroll
                for (int cg = 0; cg < 8; ++cg)
                    bn[cg] = *(const s16x8*)(p1 + ((ks + 1) * 8 + cg) * 512);
            }
            s16x8 a0 = *(const s16x8*)&ys[(ks * 2 + 0) * 512 + q * 128 + lc * 8];
            s16x8 a1 = *(const s16x8*)&ys[(ks * 2 + 1) * 512 + q * 128 + lc * 8];
#pragma unroll
            for (int cg = 0; cg < 8; ++cg) {
                acc1[0][cg] = __builtin_amdgcn_mfma_f32_16x16x32_bf16(a0, bc[cg], acc1[0][cg], 0, 0, 0);
                acc1[1][cg] = __builtin_amdgcn_mfma_f32_16x16x32_bf16(a1, bc[cg], acc1[1][cg], 0, 0, 0);
            }
        }

#pragma unroll
        for (int m = 0; m < 2; ++m)
#pragma unroll
            for (int cg = 0; cg < 8; ++cg) {
                int tile = (w * 4 + (cg >> 1)) * 2 + m;
                int base = tile * 512 + ((cg & 1) * 2 + (lc >> 3)) * 128 + (lc & 7);
#pragma unroll
                for (int j = 0; j < 4; ++j)
                    hs[base + (lr + j) * 8] = f2bf(fast_tanh(acc1[m][cg][j] + bv1[cg]));
            }
    }
    __syncthreads();

    // ========== phase 2: k = h @ W2 + b2 ; RK4 epilogue  (wave: 32r x 64c, K=1024) ==========
    {
        f32x4 acc2[2][4];
#pragma unroll
        for (int m = 0; m < 2; ++m)
#pragma unroll
            for (int cf = 0; cf < 4; ++cf)
                acc2[m][cf] = (f32x4){0.f, 0.f, 0.f, 0.f};

        s16x8 cA[4], cB[4];
#pragma unroll
        for (int cf = 0; cf < 4; ++cf)
            cA[cf] = *(const s16x8*)(p2 + cf * 512);

#pragma unroll
        for (int ks = 0; ks < 32; ++ks) {
            s16x8* bc = (ks & 1) ? cB : cA;
            s16x8* bn = (ks & 1) ? cA : cB;
            if (ks < 31) {
#pragma unroll
                for (int cf = 0; cf < 4; ++cf)
                    bn[cf] = *(const s16x8*)(p2 + ((ks + 1) * 4 + cf) * 512);
            }
            s16x8 a0 = *(const s16x8*)&hs[(ks * 2 + 0) * 512 + q * 128 + lc * 8];
            s16x8 a1 = *(const s16x8*)&hs[(ks * 2 + 1) * 512 + q * 128 + lc * 8];
#pragma unroll
            for (int cf = 0; cf < 4; ++cf) {
                acc2[0][cf] = __builtin_amdgcn_mfma_f32_16x16x32_bf16(a0, bc[cf], acc2[0][cf], 0, 0, 0);
                acc2[1][cf] = __builtin_amdgcn_mfma_f32_16x16x32_bf16(a1, bc[cf], acc2[1][cf], 0, 0, 0);
            }
        }

        const float dtv = tgrid[step + 1] - tgrid[step];
#pragma unroll
        for (int m = 0; m < 2; ++m)
#pragma unroll
            for (int cf = 0; cf < 4; ++cf) {
#pragma unroll
                for (int j = 0; j < 4; ++j) {
                    int row = row0 + m * 16 + lr + j;
                    int col = w * 64 + cf * 16 + lc;
                    size_t idx = (size_t)row * DIM + col;
                    float v = acc2[m][cf][j] + bv2[cf];
                    float yb = ybase_g[idx];
                    if (st == 0) {
                        accum[idx] = v;
                        ybf_next[idx] = f2bf(yb + 0.5f * dtv * v);
                    } else if (st == 1) {
                        accum[idx] += 2.0f * v;
                        ybf_next[idx] = f2bf(yb + 0.5f * dtv * v);
                    } else if (st == 2) {
                        accum[idx] += 2.0f * v;
                        ybf_next[idx] = f2bf(yb + dtv * v);
                    } else {
                        float y1 = yb + (dtv * (1.0f / 6.0f)) * (accum[idx] + v);
                        ynext_g[idx] = y1;
                        ybf_next[idx] = f2bf(y1);
                    }
                }
            }
    }
}

extern "C" void kernel_launch(void* const* d_in, const int* in_sizes, int n_in,
                              void* d_out, int out_size, void* d_ws, size_t ws_size,
                              hipStream_t stream) {
    (void)in_sizes; (void)n_in; (void)out_size; (void)ws_size;
    const float* x0 = (const float*)d_in[0];
    const float* t  = (const float*)d_in[1];
    const float* W1 = (const float*)d_in[2];
    const float* b1 = (const float*)d_in[3];
    const float* W2 = (const float*)d_in[4];
    const float* b2 = (const float*)d_in[5];
    float* out = (float*)d_out;

    char* ws = (char*)d_ws;
    u16*   ybf   = (u16*)  (ws);               //  4 MB [4096,512] bf16 y-arg
    float* accum = (float*)(ws + (4u  << 20)); //  8 MB [4096,512] f32
    u16*   W1P   = (u16*)  (ws + (12u << 20)); //  1 MB packed
    u16*   W2P   = (u16*)  (ws + (13u << 20)); //  1 MB packed

    init_state<<<(BATCH * DIM + 255) / 256, 256, 0, stream>>>(x0, out, ybf, BATCH * DIM);
    pack_w1<<<(HID * DIM) / 256, 256, 0, stream>>>(W1, W1P);
    pack_w2<<<(DIM * HID) / 256, 256, 0, stream>>>(W2, W2P);

    for (int s = 0; s < TSTEPS - 1; ++s) {
        const float* yb_s = out + (size_t)s * BATCH * DIM;
        float*       yn_s = out + (size_t)(s + 1) * BATCH * DIM;
        for (int st = 0; st < 4; ++st) {
            ode_stage<<<NBLK, NTHR, 0, stream>>>(ybf, b1, b2, W1P, W2P,
                                                 yb_s, yn_s, accum, ybf, t, s, st);
        }
    }
}